// Round 4
// baseline (42.563 us; speedup 1.0000x reference)
//
#include <hip/hip_runtime.h>

#define NN 32768
#define MM 4096
#define DD 32

typedef short short8 __attribute__((ext_vector_type(8)));
typedef float f32x4 __attribute__((ext_vector_type(4)));

#define ROWTILES 2     // 16-row MFMA tiles per wave -> 32 rows/wave
#define WAVES 4        // waves per block -> 128 rows/block

__device__ __forceinline__ unsigned short f2bf(float f) {
    unsigned u = __float_as_uint(f);
    unsigned r = 0x7FFFu + ((u >> 16) & 1u);
    return (unsigned short)((u + r) >> 16);
}
__device__ __forceinline__ float bf2f(unsigned short h) {
    return __uint_as_float(((unsigned)h) << 16);
}

// ---------------------------------------------------------------------------
// Prep: X is PRE-SCALED by LA = log2(e)/g^2 before the bf16 hi/lo split, so
// the MFMA dot directly produces LA*(x.y). Bx_i = -0.5*LA*||x_i||^2 (raw x),
// w_j = alpha_j * 2^(-0.5*LA*||y_j||^2). C split is unscaled.
// ---------------------------------------------------------------------------
__global__ __launch_bounds__(256) void prep_kern(
    const float* __restrict__ X, const float* __restrict__ C,
    const float* __restrict__ alphas, const float* __restrict__ sigma,
    unsigned short* __restrict__ Xh, unsigned short* __restrict__ Xl,
    unsigned short* __restrict__ Ch, unsigned short* __restrict__ Cl,
    float* __restrict__ Bx, float* __restrict__ w)
{
    int i = blockIdx.x * 256 + threadIdx.x;
    float g = sigma[0];
    float LA = 1.44269504088896340736f / (g * g);

    const float* src;
    unsigned short* dh;
    unsigned short* dl;
    int row;
    bool isX = (i < NN);
    if (isX) {
        row = i;
        src = X + (size_t)row * DD;
        dh = Xh + (size_t)row * DD;
        dl = Xl + (size_t)row * DD;
    } else {
        row = i - NN;
        if (row >= MM) return;
        src = C + (size_t)row * DD;
        dh = Ch + (size_t)row * DD;
        dl = Cl + (size_t)row * DD;
    }
    const float scale = isX ? LA : 1.0f;

    float s2 = 0.f;
#pragma unroll
    for (int q = 0; q < DD / 8; ++q) {
        float4 a = ((const float4*)src)[2 * q];
        float4 b = ((const float4*)src)[2 * q + 1];
        float vv[8] = {a.x, a.y, a.z, a.w, b.x, b.y, b.z, b.w};
        short8 hv, lv;
#pragma unroll
        for (int e = 0; e < 8; ++e) {
            float v = vv[e];
            s2 = fmaf(v, v, s2);
            float sv = v * scale;
            unsigned short h = f2bf(sv);
            hv[e] = (short)h;
            lv[e] = (short)f2bf(sv - bf2f(h));
        }
        ((short8*)dh)[q] = hv;
        ((short8*)dl)[q] = lv;
    }
    float b = -0.5f * LA * s2;
    if (isX) Bx[row] = b;
    else     w[row] = alphas[row] * exp2f(b);
}

// ---------------------------------------------------------------------------
// Main: LDS-staged double-bf16 MFMA GEMM fused with exp epilogue.
// Block = 4 waves x 32 rows = 128 rows; grid.y = MS slices of M (MPER cols).
// LDS: [MPER][32] bf16 hi/lo slabs + w slice = 16.5 KB -> high occupancy.
// __launch_bounds__(256,8): target 8 waves/SIMD (VGPR <= 64).
// Accumulator seeded with Bx; epilogue = exp2 + fmac only.
// ---------------------------------------------------------------------------
template <int MS>
__global__ __launch_bounds__(256, 8) void rbf_mfma_lds(
    const unsigned short* __restrict__ Xh, const unsigned short* __restrict__ Xl,
    const unsigned short* __restrict__ Ch, const unsigned short* __restrict__ Cl,
    const float* __restrict__ Bx, const float* __restrict__ w,
    float* __restrict__ part)
{
    constexpr int MPER = MM / MS;
    constexpr int NT = MPER / 16;
    __shared__ unsigned short sCh[MPER * DD];
    __shared__ unsigned short sCl[MPER * DD];
    __shared__ float sw[MPER];

    const int tid = threadIdx.x;
    const int wave = tid >> 6;
    const int lane = tid & 63;
    const int l15 = lane & 15;
    const int lhi = lane >> 4;
    const int rowbase = (blockIdx.x * WAVES + wave) * (16 * ROWTILES);
    const int slice = blockIdx.y;
    const int j0 = slice * MPER;

    // ---- stage C slice (hi+lo) and w slice into LDS, vectorized & linear ----
    {
        const float4* gh = (const float4*)(Ch + (size_t)j0 * DD);
        const float4* gl = (const float4*)(Cl + (size_t)j0 * DD);
        float4* lh = (float4*)sCh;
        float4* ll = (float4*)sCl;
        constexpr int NV = MPER * DD / 8;  // 16B chunks per slab
#pragma unroll
        for (int o = tid; o < NV; o += 256) {
            lh[o] = gh[o];
            ll[o] = gl[o];
        }
        if (tid < MPER) sw[tid] = w[j0 + tid];
    }

    // ---- A fragments (hi/lo) + Bx seeds, loaded while staging is in flight --
    short8 ah[ROWTILES], al[ROWTILES];
#pragma unroll
    for (int t = 0; t < ROWTILES; ++t) {
        int r = rowbase + t * 16 + l15;
        ah[t] = *(const short8*)(Xh + (size_t)r * DD + lhi * 8);
        al[t] = *(const short8*)(Xl + (size_t)r * DD + lhi * 8);
    }
    f32x4 bx[ROWTILES];
#pragma unroll
    for (int t = 0; t < ROWTILES; ++t) {
        float4 v = *(const float4*)&Bx[rowbase + t * 16 + lhi * 4];
        bx[t][0] = v.x; bx[t][1] = v.y; bx[t][2] = v.z; bx[t][3] = v.w;
    }

    f32x4 acc[ROWTILES];
#pragma unroll
    for (int t = 0; t < ROWTILES; ++t) acc[t] = (f32x4){0.f, 0.f, 0.f, 0.f};

    __syncthreads();

    // ---- main loop: B-fragments from LDS, 3-MFMA double-bf16, fused exp ----
#pragma unroll 2
    for (int jt = 0; jt < NT; ++jt) {
        const int r = jt * 16 + l15;
        short8 bh = *(const short8*)&sCh[r * DD + lhi * 8];
        short8 bl = *(const short8*)&sCl[r * DD + lhi * 8];
        float wj = sw[r];
#pragma unroll
        for (int t = 0; t < ROWTILES; ++t) {
            f32x4 d = bx[t];
            d = __builtin_amdgcn_mfma_f32_16x16x32_bf16(ah[t], bl, d, 0, 0, 0);
            d = __builtin_amdgcn_mfma_f32_16x16x32_bf16(al[t], bh, d, 0, 0, 0);
            d = __builtin_amdgcn_mfma_f32_16x16x32_bf16(ah[t], bh, d, 0, 0, 0);
#pragma unroll
            for (int rr = 0; rr < 4; ++rr)
                acc[t][rr] = fmaf(wj, __builtin_amdgcn_exp2f(d[rr]), acc[t][rr]);
        }
    }

    // ---- reduce over the 16 columns (lane bits 0..3), store float4 ----------
#pragma unroll
    for (int t = 0; t < ROWTILES; ++t)
#pragma unroll
        for (int rr = 0; rr < 4; ++rr) {
            float v = acc[t][rr];
            v += __shfl_xor(v, 1, 64);
            v += __shfl_xor(v, 2, 64);
            v += __shfl_xor(v, 4, 64);
            v += __shfl_xor(v, 8, 64);
            acc[t][rr] = v;
        }
    if (l15 == 0) {
#pragma unroll
        for (int t = 0; t < ROWTILES; ++t)
            *(f32x4*)&part[(size_t)slice * NN + rowbase + t * 16 + lhi * 4] = acc[t];
    }
}

template <int MS>
__global__ __launch_bounds__(256) void reduce_kern(const float* __restrict__ part,
                                                   float* __restrict__ out) {
    int i = blockIdx.x * 256 + threadIdx.x;
    float s = 0.f;
#pragma unroll
    for (int k = 0; k < MS; ++k) s += part[(size_t)k * NN + i];
    out[i] = s;
}

// ---------------------------------------------------------------------------
// Fallback (round-1 VALU path) in case ws_size is too small.
// ---------------------------------------------------------------------------
__global__ __launch_bounds__(256) void wkern(const float* __restrict__ C,
                                             const float* __restrict__ alphas,
                                             const float* __restrict__ sigma,
                                             float* __restrict__ w) {
    int j = blockIdx.x * 256 + threadIdx.x;
    if (j >= MM) return;
    float g = sigma[0];
    float inv_g2 = 1.0f / (g * g);
    const float4* cp = (const float4*)(C + (size_t)j * DD);
    float y2 = 0.f;
#pragma unroll
    for (int q = 0; q < DD / 4; ++q) {
        float4 v = cp[q];
        y2 = fmaf(v.x, v.x, y2);
        y2 = fmaf(v.y, v.y, y2);
        y2 = fmaf(v.z, v.z, y2);
        y2 = fmaf(v.w, v.w, y2);
    }
    w[j] = alphas[j] * exp2f(-0.5f * inv_g2 * 1.44269504088896340736f * y2);
}

__global__ __launch_bounds__(128) void rbf_valu(const float* __restrict__ X,
                                                const float* __restrict__ C,
                                                const float* __restrict__ w,
                                                const float* __restrict__ sigma,
                                                float* __restrict__ out) {
    const int row = blockIdx.x * 128 + threadIdx.x;
    const float g = sigma[0];
    const float A = 1.44269504088896340736f / (g * g);
    float x[DD];
    const float4* xp = (const float4*)(X + (size_t)row * DD);
#pragma unroll
    for (int q = 0; q < DD / 4; ++q) {
        float4 v = xp[q];
        x[4 * q + 0] = v.x; x[4 * q + 1] = v.y;
        x[4 * q + 2] = v.z; x[4 * q + 3] = v.w;
    }
    float x2 = 0.f;
#pragma unroll
    for (int d = 0; d < DD; ++d) x2 = fmaf(x[d], x[d], x2);
    const float B = -0.5f * A * x2;
    float acc = 0.f;
#pragma unroll 2
    for (int j = 0; j < MM; ++j) {
        const float* cj = C + (size_t)j * DD;
        float d0 = 0.f, d1 = 0.f, d2 = 0.f, d3 = 0.f;
#pragma unroll
        for (int d = 0; d < DD; d += 4) {
            d0 = fmaf(cj[d + 0], x[d + 0], d0);
            d1 = fmaf(cj[d + 1], x[d + 1], d1);
            d2 = fmaf(cj[d + 2], x[d + 2], d2);
            d3 = fmaf(cj[d + 3], x[d + 3], d3);
        }
        float dot = (d0 + d1) + (d2 + d3);
        acc = fmaf(w[j], exp2f(fmaf(dot, A, B)), acc);
    }
    out[row] = acc;
}

extern "C" void kernel_launch(void* const* d_in, const int* in_sizes, int n_in,
                              void* d_out, int out_size, void* d_ws, size_t ws_size,
                              hipStream_t stream) {
    const float* X  = (const float*)d_in[0];
    const float* C  = (const float*)d_in[1];
    const float* al = (const float*)d_in[2];
    const float* sg = (const float*)d_in[3];
    float* out = (float*)d_out;

    // Workspace layout (all 16B aligned).
    size_t off = 0;
    unsigned short* Xh = (unsigned short*)((char*)d_ws + off); off += (size_t)NN * DD * 2;
    unsigned short* Xl = (unsigned short*)((char*)d_ws + off); off += (size_t)NN * DD * 2;
    unsigned short* Ch = (unsigned short*)((char*)d_ws + off); off += (size_t)MM * DD * 2;
    unsigned short* Cl = (unsigned short*)((char*)d_ws + off); off += (size_t)MM * DD * 2;
    float* Bx = (float*)((char*)d_ws + off); off += (size_t)NN * 4;
    float* w  = (float*)((char*)d_ws + off); off += (size_t)MM * 4;
    float* part = (float*)((char*)d_ws + off);
    const size_t base = off;

    const size_t need32 = base + (size_t)32 * NN * 4;
    const size_t need8  = base + (size_t)8 * NN * 4;

    if (ws_size >= need8) {
        prep_kern<<<(NN + MM) / 256, 256, 0, stream>>>(X, C, al, sg, Xh, Xl, Ch, Cl, Bx, w);
        if (ws_size >= need32) {
            dim3 grid(NN / (WAVES * 16 * ROWTILES), 32);
            rbf_mfma_lds<32><<<grid, 64 * WAVES, 0, stream>>>(Xh, Xl, Ch, Cl, Bx, w, part);
            reduce_kern<32><<<NN / 256, 256, 0, stream>>>(part, out);
        } else {
            dim3 grid(NN / (WAVES * 16 * ROWTILES), 8);
            rbf_mfma_lds<8><<<grid, 64 * WAVES, 0, stream>>>(Xh, Xl, Ch, Cl, Bx, w, part);
            reduce_kern<8><<<NN / 256, 256, 0, stream>>>(part, out);
        }
    } else {
        // Fallback: fp32 VALU path, needs only 16 KB for w.
        float* wf = (float*)d_ws;
        wkern<<<MM / 256, 256, 0, stream>>>(C, al, sg, wf);
        rbf_valu<<<NN / 128, 128, 0, stream>>>(X, C, wf, sg, out);
    }
}

// Round 5
// 40.001 us; speedup vs baseline: 1.0640x; 1.0640x over previous
//
#include <hip/hip_runtime.h>

#define NN 32768
#define MM 4096
#define DD 32

typedef short short8 __attribute__((ext_vector_type(8)));
typedef float f32x4 __attribute__((ext_vector_type(4)));

#define ROWTILES 4     // 16-row MFMA tiles per wave -> 64 rows/wave
#define WAVES 4        // waves per block -> 256 rows/block

__device__ __forceinline__ unsigned short f2bf(float f) {
    unsigned u = __float_as_uint(f);
    unsigned r = 0x7FFFu + ((u >> 16) & 1u);
    return (unsigned short)((u + r) >> 16);
}
__device__ __forceinline__ float bf2f(unsigned short h) {
    return __uint_as_float(((unsigned)h) << 16);
}

// ---------------------------------------------------------------------------
// Prep: X is PRE-SCALED by LA = log2(e)/g^2 before the bf16 hi/lo split, so
// the MFMA dot directly produces LA*(x.y). Bx_i = -0.5*LA*||x_i||^2 (raw x),
// w_j = alpha_j * 2^(-0.5*LA*||y_j||^2). C split is unscaled.
// ---------------------------------------------------------------------------
__global__ __launch_bounds__(256) void prep_kern(
    const float* __restrict__ X, const float* __restrict__ C,
    const float* __restrict__ alphas, const float* __restrict__ sigma,
    unsigned short* __restrict__ Xh, unsigned short* __restrict__ Xl,
    unsigned short* __restrict__ Ch, unsigned short* __restrict__ Cl,
    float* __restrict__ Bx, float* __restrict__ w)
{
    int i = blockIdx.x * 256 + threadIdx.x;
    float g = sigma[0];
    float LA = 1.44269504088896340736f / (g * g);

    const float* src;
    unsigned short* dh;
    unsigned short* dl;
    int row;
    bool isX = (i < NN);
    if (isX) {
        row = i;
        src = X + (size_t)row * DD;
        dh = Xh + (size_t)row * DD;
        dl = Xl + (size_t)row * DD;
    } else {
        row = i - NN;
        if (row >= MM) return;
        src = C + (size_t)row * DD;
        dh = Ch + (size_t)row * DD;
        dl = Cl + (size_t)row * DD;
    }
    const float scale = isX ? LA : 1.0f;

    float s2 = 0.f;
#pragma unroll
    for (int q = 0; q < DD / 8; ++q) {
        float4 a = ((const float4*)src)[2 * q];
        float4 b = ((const float4*)src)[2 * q + 1];
        float vv[8] = {a.x, a.y, a.z, a.w, b.x, b.y, b.z, b.w};
        short8 hv, lv;
#pragma unroll
        for (int e = 0; e < 8; ++e) {
            float v = vv[e];
            s2 = fmaf(v, v, s2);
            float sv = v * scale;
            unsigned short h = f2bf(sv);
            hv[e] = (short)h;
            lv[e] = (short)f2bf(sv - bf2f(h));
        }
        ((short8*)dh)[q] = hv;
        ((short8*)dl)[q] = lv;
    }
    float b = -0.5f * LA * s2;
    if (isX) Bx[row] = b;
    else     w[row] = alphas[row] * exp2f(b);
}

// ---------------------------------------------------------------------------
// Main: LDS-staged double-bf16 MFMA GEMM fused with exp epilogue.
// LDS layout is XOR-swizzled: byte ^= (row&7)<<4 within each 8-row stripe.
//   write: chunk o (16B) -> byte 16*(o ^ ((o>>2)&7))
//   read : row r, quad lhi -> byte (r*64 + lhi*16) ^ ((r&7)<<4)
// Read bank-groups (bits01 = lhi^(r&3), bit2 = r0^r2) are uniform 8 lanes
// per 4-bank group = conflict-free (was 8-way conflicted unswizzled).
// 1-deep LDS prefetch pipeline; accumulator seeded with Bx so the epilogue
// is exp2 + fmac only.
// ---------------------------------------------------------------------------
template <int MS>
__global__ __launch_bounds__(256, 4) void rbf_mfma_lds(
    const unsigned short* __restrict__ Xh, const unsigned short* __restrict__ Xl,
    const unsigned short* __restrict__ Ch, const unsigned short* __restrict__ Cl,
    const float* __restrict__ Bx, const float* __restrict__ w,
    float* __restrict__ part)
{
    constexpr int MPER = MM / MS;
    constexpr int NT = MPER / 16;
    __shared__ unsigned short sCh[MPER * DD];
    __shared__ unsigned short sCl[MPER * DD];
    __shared__ float sw[MPER];

    const int tid = threadIdx.x;
    const int wave = tid >> 6;
    const int lane = tid & 63;
    const int l15 = lane & 15;
    const int lhi = lane >> 4;
    const int rowbase = (blockIdx.x * WAVES + wave) * (16 * ROWTILES);
    const int slice = blockIdx.y;
    const int j0 = slice * MPER;

    char* lh = (char*)sCh;
    char* ll = (char*)sCl;

    // ---- stage C slice (hi+lo, swizzled) and w slice into LDS --------------
    {
        const float4* gh = (const float4*)(Ch + (size_t)j0 * DD);
        const float4* gl = (const float4*)(Cl + (size_t)j0 * DD);
        constexpr int NV = MPER * DD / 8;  // 16B chunks per slab
#pragma unroll
        for (int o = tid; o < NV; o += 256) {
            int b = 16 * (o ^ ((o >> 2) & 7));
            *(float4*)(lh + b) = gh[o];
            *(float4*)(ll + b) = gl[o];
        }
        if (tid < MPER) sw[tid] = w[j0 + tid];
    }

    // ---- A fragments (hi/lo) + Bx seeds, loaded while staging in flight ----
    short8 ah[ROWTILES], al[ROWTILES];
#pragma unroll
    for (int t = 0; t < ROWTILES; ++t) {
        int r = rowbase + t * 16 + l15;
        ah[t] = *(const short8*)(Xh + (size_t)r * DD + lhi * 8);
        al[t] = *(const short8*)(Xl + (size_t)r * DD + lhi * 8);
    }
    f32x4 bx[ROWTILES];
#pragma unroll
    for (int t = 0; t < ROWTILES; ++t) {
        float4 v = *(const float4*)&Bx[rowbase + t * 16 + lhi * 4];
        bx[t][0] = v.x; bx[t][1] = v.y; bx[t][2] = v.z; bx[t][3] = v.w;
    }

    f32x4 acc[ROWTILES];
#pragma unroll
    for (int t = 0; t < ROWTILES; ++t) acc[t] = (f32x4){0.f, 0.f, 0.f, 0.f};

    __syncthreads();

    // ---- main loop: swizzled ds_read_b128, 3-MFMA double-bf16, fused exp ---
    short8 bh, bl;
    float wj;
    {
        int b = (l15 * 64 + lhi * 16) ^ ((l15 & 7) << 4);
        bh = *(const short8*)(lh + b);
        bl = *(const short8*)(ll + b);
        wj = sw[l15];
    }
#pragma unroll 2
    for (int jt = 0; jt < NT; ++jt) {
        short8 nbh = bh, nbl = bl;
        float nwj = wj;
        if (jt + 1 < NT) {
            int r = (jt + 1) * 16 + l15;
            int b = (r * 64 + lhi * 16) ^ ((r & 7) << 4);
            nbh = *(const short8*)(lh + b);
            nbl = *(const short8*)(ll + b);
            nwj = sw[r];
        }
#pragma unroll
        for (int t = 0; t < ROWTILES; ++t) {
            f32x4 d = bx[t];
            d = __builtin_amdgcn_mfma_f32_16x16x32_bf16(ah[t], bl, d, 0, 0, 0);
            d = __builtin_amdgcn_mfma_f32_16x16x32_bf16(al[t], bh, d, 0, 0, 0);
            d = __builtin_amdgcn_mfma_f32_16x16x32_bf16(ah[t], bh, d, 0, 0, 0);
#pragma unroll
            for (int rr = 0; rr < 4; ++rr)
                acc[t][rr] = fmaf(wj, __builtin_amdgcn_exp2f(d[rr]), acc[t][rr]);
        }
        bh = nbh; bl = nbl; wj = nwj;
    }

    // ---- reduce over the 16 columns (lane bits 0..3), store float4 ---------
#pragma unroll
    for (int t = 0; t < ROWTILES; ++t)
#pragma unroll
        for (int rr = 0; rr < 4; ++rr) {
            float v = acc[t][rr];
            v += __shfl_xor(v, 1, 64);
            v += __shfl_xor(v, 2, 64);
            v += __shfl_xor(v, 4, 64);
            v += __shfl_xor(v, 8, 64);
            acc[t][rr] = v;
        }
    if (l15 == 0) {
#pragma unroll
        for (int t = 0; t < ROWTILES; ++t)
            *(f32x4*)&part[(size_t)slice * NN + rowbase + t * 16 + lhi * 4] = acc[t];
    }
}

template <int MS>
__global__ __launch_bounds__(256) void reduce_kern(const float* __restrict__ part,
                                                   float* __restrict__ out) {
    int i = blockIdx.x * 256 + threadIdx.x;
    float s = 0.f;
#pragma unroll
    for (int k = 0; k < MS; ++k) s += part[(size_t)k * NN + i];
    out[i] = s;
}

// ---------------------------------------------------------------------------
// Fallback (round-1 VALU path) in case ws_size is too small.
// ---------------------------------------------------------------------------
__global__ __launch_bounds__(256) void wkern(const float* __restrict__ C,
                                             const float* __restrict__ alphas,
                                             const float* __restrict__ sigma,
                                             float* __restrict__ w) {
    int j = blockIdx.x * 256 + threadIdx.x;
    if (j >= MM) return;
    float g = sigma[0];
    float inv_g2 = 1.0f / (g * g);
    const float4* cp = (const float4*)(C + (size_t)j * DD);
    float y2 = 0.f;
#pragma unroll
    for (int q = 0; q < DD / 4; ++q) {
        float4 v = cp[q];
        y2 = fmaf(v.x, v.x, y2);
        y2 = fmaf(v.y, v.y, y2);
        y2 = fmaf(v.z, v.z, y2);
        y2 = fmaf(v.w, v.w, y2);
    }
    w[j] = alphas[j] * exp2f(-0.5f * inv_g2 * 1.44269504088896340736f * y2);
}

__global__ __launch_bounds__(128) void rbf_valu(const float* __restrict__ X,
                                                const float* __restrict__ C,
                                                const float* __restrict__ w,
                                                const float* __restrict__ sigma,
                                                float* __restrict__ out) {
    const int row = blockIdx.x * 128 + threadIdx.x;
    const float g = sigma[0];
    const float A = 1.44269504088896340736f / (g * g);
    float x[DD];
    const float4* xp = (const float4*)(X + (size_t)row * DD);
#pragma unroll
    for (int q = 0; q < DD / 4; ++q) {
        float4 v = xp[q];
        x[4 * q + 0] = v.x; x[4 * q + 1] = v.y;
        x[4 * q + 2] = v.z; x[4 * q + 3] = v.w;
    }
    float x2 = 0.f;
#pragma unroll
    for (int d = 0; d < DD; ++d) x2 = fmaf(x[d], x[d], x2);
    const float B = -0.5f * A * x2;
    float acc = 0.f;
#pragma unroll 2
    for (int j = 0; j < MM; ++j) {
        const float* cj = C + (size_t)j * DD;
        float d0 = 0.f, d1 = 0.f, d2 = 0.f, d3 = 0.f;
#pragma unroll
        for (int d = 0; d < DD; d += 4) {
            d0 = fmaf(cj[d + 0], x[d + 0], d0);
            d1 = fmaf(cj[d + 1], x[d + 1], d1);
            d2 = fmaf(cj[d + 2], x[d + 2], d2);
            d3 = fmaf(cj[d + 3], x[d + 3], d3);
        }
        float dot = (d0 + d1) + (d2 + d3);
        acc = fmaf(w[j], exp2f(fmaf(dot, A, B)), acc);
    }
    out[row] = acc;
}

extern "C" void kernel_launch(void* const* d_in, const int* in_sizes, int n_in,
                              void* d_out, int out_size, void* d_ws, size_t ws_size,
                              hipStream_t stream) {
    const float* X  = (const float*)d_in[0];
    const float* C  = (const float*)d_in[1];
    const float* al = (const float*)d_in[2];
    const float* sg = (const float*)d_in[3];
    float* out = (float*)d_out;

    // Workspace layout (all 16B aligned).
    size_t off = 0;
    unsigned short* Xh = (unsigned short*)((char*)d_ws + off); off += (size_t)NN * DD * 2;
    unsigned short* Xl = (unsigned short*)((char*)d_ws + off); off += (size_t)NN * DD * 2;
    unsigned short* Ch = (unsigned short*)((char*)d_ws + off); off += (size_t)MM * DD * 2;
    unsigned short* Cl = (unsigned short*)((char*)d_ws + off); off += (size_t)MM * DD * 2;
    float* Bx = (float*)((char*)d_ws + off); off += (size_t)NN * 4;
    float* w  = (float*)((char*)d_ws + off); off += (size_t)MM * 4;
    float* part = (float*)((char*)d_ws + off);
    const size_t base = off;

    const size_t need32 = base + (size_t)32 * NN * 4;
    const size_t need8  = base + (size_t)8 * NN * 4;

    if (ws_size >= need8) {
        prep_kern<<<(NN + MM) / 256, 256, 0, stream>>>(X, C, al, sg, Xh, Xl, Ch, Cl, Bx, w);
        if (ws_size >= need32) {
            dim3 grid(NN / (WAVES * 16 * ROWTILES), 32);
            rbf_mfma_lds<32><<<grid, 64 * WAVES, 0, stream>>>(Xh, Xl, Ch, Cl, Bx, w, part);
            reduce_kern<32><<<NN / 256, 256, 0, stream>>>(part, out);
        } else {
            dim3 grid(NN / (WAVES * 16 * ROWTILES), 8);
            rbf_mfma_lds<8><<<grid, 64 * WAVES, 0, stream>>>(Xh, Xl, Ch, Cl, Bx, w, part);
            reduce_kern<8><<<NN / 256, 256, 0, stream>>>(part, out);
        }
    } else {
        // Fallback: fp32 VALU path, needs only 16 KB for w.
        float* wf = (float*)d_ws;
        wkern<<<MM / 256, 256, 0, stream>>>(C, al, sg, wf);
        rbf_valu<<<NN / 128, 128, 0, stream>>>(X, C, wf, sg, out);
    }
}